// Round 1
// baseline (655.231 us; speedup 1.0000x reference)
//
#include <hip/hip_runtime.h>

// LayerNorm backward: B=4, S=4096, H=2048, fp32.
// Outputs concatenated: dx [B*S*H] ++ dgamma [H] ++ dbeta [H].
//
// R1: latency-bound fix. Previous version: 512 blocks = 8 waves/CU (Occupancy 21%,
// VALUBusy 6%, 2.05 TB/s). This version: RPB 32->8 => 2048 blocks = 32 waves/CU,
// one barrier per row (double-buffered reduction scratch), all 4 stream loads
// issued up front, dyv retired into dg/db before the reduce to stay <=64 VGPRs.

constexpr int Bc = 4, Sc = 4096, Hc = 2048;
constexpr int ROWS = Bc * Sc;        // 16384
constexpr int THREADS = 256;         // 4 waves; each thread owns 8 columns
constexpr int RPB = 8;               // rows per block
constexpr int NBLK = ROWS / RPB;     // 2048 blocks -> 8 blocks/CU = 32 waves/CU

__device__ __forceinline__ void load8(const float* __restrict__ p, int c0, int c1, float v[8]) {
    float4 a = *(const float4*)(p + c0);
    float4 b = *(const float4*)(p + c1);
    v[0] = a.x; v[1] = a.y; v[2] = a.z; v[3] = a.w;
    v[4] = b.x; v[5] = b.y; v[6] = b.z; v[7] = b.w;
}

__device__ __forceinline__ void store8(float* __restrict__ p, int c0, int c1, const float v[8]) {
    float4 a = {v[0], v[1], v[2], v[3]};
    float4 b = {v[4], v[5], v[6], v[7]};
    *(float4*)(p + c0) = a;
    *(float4*)(p + c1) = b;
}

__global__ __launch_bounds__(THREADS, 8) void ln_bwd_kernel(
    const float* __restrict__ dy, const float* __restrict__ x1,
    const float* __restrict__ x2, const float* __restrict__ rstd,
    const float* __restrict__ mean, const float* __restrict__ gamma,
    const float* __restrict__ dsum, float* __restrict__ out)
{
    float* out_x = out;
    float* out_g = out + (size_t)ROWS * Hc;
    float* out_b = out_g + Hc;

    const int t   = threadIdx.x;
    const int wid = t >> 6;                 // wave id (wave = 64 lanes)
    const int c0  = t * 4;                  // first float4 segment
    const int c1  = (Hc / 2) + t * 4;       // second float4 segment

    // Double-buffered so each row needs exactly ONE barrier (no WAR barrier):
    // row r writes red[r&1]; the write of red[r&1] two rows later is fenced by
    // the intervening row's barrier.
    __shared__ float red[2][4][3];

    float g[8];
    {
        float4 a = *(const float4*)(gamma + c0);
        float4 b = *(const float4*)(gamma + c1);
        g[0] = a.x; g[1] = a.y; g[2] = a.z; g[3] = a.w;
        g[4] = b.x; g[5] = b.y; g[6] = b.z; g[7] = b.w;
    }

    float dg[8], db[8];
    #pragma unroll
    for (int i = 0; i < 8; ++i) { dg[i] = 0.f; db[i] = 0.f; }

    const int row0 = blockIdx.x * RPB;
    const float inv_d = 1.0f / (float)Hc;

    for (int r = 0; r < RPB; ++r) {
        const int row = row0 + r;
        const size_t base = (size_t)row * Hc;
        const float mu = mean[row];
        const float rs = rstd[row];

        // Issue all four streams up front: 8x 16B loads in flight before any use.
        float dyv[8], xh[8], p[8], ds[8];
        load8(dy + base, c0, c1, dyv);
        load8(dsum + base, c0, c1, ds);
        {
            float av[8], bv[8];
            load8(x1 + base, c0, c1, av);
            load8(x2 + base, c0, c1, bv);
            #pragma unroll
            for (int i = 0; i < 8; ++i) xh[i] = av[i] + bv[i] - mu;
        }
        #pragma unroll
        for (int i = 0; i < 8; ++i) p[i] = dyv[i] * g[i];

        // Retire dyv into the param-grad accumulators BEFORE the reduce so its
        // 8 registers are dead across the shuffle chain (keeps VGPR <= 64).
        #pragma unroll
        for (int i = 0; i < 8; ++i) { dg[i] += dyv[i] * xh[i] * rs; db[i] += dyv[i]; }

        // Three row sums: S1 = sum(p*xh), S2 = sum(p), S3 = sum(xh)
        float s1 = 0.f, s2 = 0.f, s3 = 0.f;
        #pragma unroll
        for (int i = 0; i < 8; ++i) { s1 += p[i] * xh[i]; s2 += p[i]; s3 += xh[i]; }

        #pragma unroll
        for (int off = 32; off > 0; off >>= 1) {
            s1 += __shfl_xor(s1, off);
            s2 += __shfl_xor(s2, off);
            s3 += __shfl_xor(s3, off);
        }
        const int buf = r & 1;
        if ((t & 63) == 0) { red[buf][wid][0] = s1; red[buf][wid][1] = s2; red[buf][wid][2] = s3; }
        __syncthreads();
        const float S1 = red[buf][0][0] + red[buf][1][0] + red[buf][2][0] + red[buf][3][0];
        const float S2 = red[buf][0][1] + red[buf][1][1] + red[buf][2][1] + red[buf][3][1];
        const float S3 = red[buf][0][2] + red[buf][1][2] + red[buf][2][2] + red[buf][3][2];

        const float pd_var  = -0.5f * rs * rs * rs * S1;
        const float pd_mean = -rs * S2 - 2.0f * inv_d * pd_var * S3;
        const float k2 = 2.0f * inv_d * pd_var;
        const float km = inv_d * pd_mean;

        float o[8];
        #pragma unroll
        for (int i = 0; i < 8; ++i) o[i] = p[i] * rs + k2 * xh[i] + km + ds[i];
        store8(out_x + base, c0, c1, o);
    }

    // One atomic per column per block: 2048 adds/address total, spread over
    // 4096 addresses (dgamma) + 4096 (dbeta) -> parallel across TCC channels.
    #pragma unroll
    for (int i = 0; i < 4; ++i) atomicAdd(out_g + c0 + i, dg[i]);
    #pragma unroll
    for (int i = 0; i < 4; ++i) atomicAdd(out_g + c1 + i, dg[4 + i]);
    #pragma unroll
    for (int i = 0; i < 4; ++i) atomicAdd(out_b + c0 + i, db[i]);
    #pragma unroll
    for (int i = 0; i < 4; ++i) atomicAdd(out_b + c1 + i, db[4 + i]);
}

extern "C" void kernel_launch(void* const* d_in, const int* in_sizes, int n_in,
                              void* d_out, int out_size, void* d_ws, size_t ws_size,
                              hipStream_t stream) {
    const float* dy    = (const float*)d_in[0];
    const float* x1    = (const float*)d_in[1];
    const float* x2    = (const float*)d_in[2];
    const float* rstd  = (const float*)d_in[3];
    const float* mean  = (const float*)d_in[4];
    const float* gamma = (const float*)d_in[5];
    const float* dsum  = (const float*)d_in[6];
    float* out = (float*)d_out;

    // Zero dgamma/dbeta region (d_out is poisoned 0xAA before every launch).
    hipMemsetAsync(out + (size_t)ROWS * Hc, 0, 2 * Hc * sizeof(float), stream);

    ln_bwd_kernel<<<NBLK, THREADS, 0, stream>>>(dy, x1, x2, rstd, mean, gamma, dsum, out);
}

// Round 2
// 511.991 us; speedup vs baseline: 1.2798x; 1.2798x over previous
//
#include <hip/hip_runtime.h>

// LayerNorm backward: B=4, S=4096, H=2048, fp32.
// Outputs concatenated: dx [B*S*H] ++ dgamma [H] ++ dbeta [H].
//
// R2: kill the atomic reduction. R1 post-mortem: 8.4M device-scope fp32
// atomicAdds to the 16KB dgamma/dbeta region generated ~52B of HBM RMW
// traffic each (line ping-pong across 8 non-coherent XCD L2s) and ~190us of
// serialized tail. Replace with per-block partials in d_ws (33.5MB of clean
// coalesced stores) + a 512-block reduction kernel (131K atomics, 32/addr).

constexpr int Bc = 4, Sc = 4096, Hc = 2048;
constexpr int ROWS = Bc * Sc;        // 16384
constexpr int THREADS = 256;         // 4 waves; each thread owns 8 columns
constexpr int RPB = 8;               // rows per block
constexpr int NBLK = ROWS / RPB;     // 2048 blocks -> 8 blocks/CU = 32 waves/CU

__device__ __forceinline__ void load8(const float* __restrict__ p, int c0, int c1, float v[8]) {
    float4 a = *(const float4*)(p + c0);
    float4 b = *(const float4*)(p + c1);
    v[0] = a.x; v[1] = a.y; v[2] = a.z; v[3] = a.w;
    v[4] = b.x; v[5] = b.y; v[6] = b.z; v[7] = b.w;
}

__device__ __forceinline__ void store8(float* __restrict__ p, int c0, int c1, const float v[8]) {
    float4 a = {v[0], v[1], v[2], v[3]};
    float4 b = {v[4], v[5], v[6], v[7]};
    *(float4*)(p + c0) = a;
    *(float4*)(p + c1) = b;
}

__global__ __launch_bounds__(THREADS, 8) void ln_bwd_main(
    const float* __restrict__ dy, const float* __restrict__ x1,
    const float* __restrict__ x2, const float* __restrict__ rstd,
    const float* __restrict__ mean, const float* __restrict__ gamma,
    const float* __restrict__ dsum, float* __restrict__ out,
    float* __restrict__ ws)
{
    float* out_x = out;

    const int t   = threadIdx.x;
    const int wid = t >> 6;                 // wave id (wave = 64 lanes)
    const int c0  = t * 4;                  // first float4 segment
    const int c1  = (Hc / 2) + t * 4;       // second float4 segment

    // Double-buffered so each row needs exactly ONE barrier (no WAR barrier).
    __shared__ float red[2][4][3];

    float g[8];
    {
        float4 a = *(const float4*)(gamma + c0);
        float4 b = *(const float4*)(gamma + c1);
        g[0] = a.x; g[1] = a.y; g[2] = a.z; g[3] = a.w;
        g[4] = b.x; g[5] = b.y; g[6] = b.z; g[7] = b.w;
    }

    float dg[8], db[8];
    #pragma unroll
    for (int i = 0; i < 8; ++i) { dg[i] = 0.f; db[i] = 0.f; }

    const int row0 = blockIdx.x * RPB;
    const float inv_d = 1.0f / (float)Hc;

    for (int r = 0; r < RPB; ++r) {
        const int row = row0 + r;
        const size_t base = (size_t)row * Hc;
        const float mu = mean[row];
        const float rs = rstd[row];

        // Issue all four streams up front: 8x 16B loads in flight before any use.
        float dyv[8], xh[8], p[8], ds[8];
        load8(dy + base, c0, c1, dyv);
        load8(dsum + base, c0, c1, ds);
        {
            float av[8], bv[8];
            load8(x1 + base, c0, c1, av);
            load8(x2 + base, c0, c1, bv);
            #pragma unroll
            for (int i = 0; i < 8; ++i) xh[i] = av[i] + bv[i] - mu;
        }
        #pragma unroll
        for (int i = 0; i < 8; ++i) p[i] = dyv[i] * g[i];

        // Retire dyv into the param-grad accumulators BEFORE the reduce so its
        // registers are dead across the shuffle chain.
        #pragma unroll
        for (int i = 0; i < 8; ++i) { dg[i] += dyv[i] * xh[i] * rs; db[i] += dyv[i]; }

        // Three row sums: S1 = sum(p*xh), S2 = sum(p), S3 = sum(xh)
        float s1 = 0.f, s2 = 0.f, s3 = 0.f;
        #pragma unroll
        for (int i = 0; i < 8; ++i) { s1 += p[i] * xh[i]; s2 += p[i]; s3 += xh[i]; }

        #pragma unroll
        for (int off = 32; off > 0; off >>= 1) {
            s1 += __shfl_xor(s1, off);
            s2 += __shfl_xor(s2, off);
            s3 += __shfl_xor(s3, off);
        }
        const int buf = r & 1;
        if ((t & 63) == 0) { red[buf][wid][0] = s1; red[buf][wid][1] = s2; red[buf][wid][2] = s3; }
        __syncthreads();
        const float S1 = red[buf][0][0] + red[buf][1][0] + red[buf][2][0] + red[buf][3][0];
        const float S2 = red[buf][0][1] + red[buf][1][1] + red[buf][2][1] + red[buf][3][1];
        const float S3 = red[buf][0][2] + red[buf][1][2] + red[buf][2][2] + red[buf][3][2];

        const float pd_var  = -0.5f * rs * rs * rs * S1;
        const float pd_mean = -rs * S2 - 2.0f * inv_d * pd_var * S3;
        const float k2 = 2.0f * inv_d * pd_var;
        const float km = inv_d * pd_mean;

        float o[8];
        #pragma unroll
        for (int i = 0; i < 8; ++i) o[i] = p[i] * rs + k2 * xh[i] + km + ds[i];
        store8(out_x + base, c0, c1, o);
    }

    // Per-block partials: plain coalesced stores, NO atomics.
    // ws layout: [2][NBLK][Hc] -- dgamma partials then dbeta partials.
    float* wsg = ws + (size_t)blockIdx.x * Hc;
    float* wsb = ws + (size_t)NBLK * Hc + (size_t)blockIdx.x * Hc;
    store8(wsg, c0, c1, dg);
    store8(wsb, c0, c1, db);
}

// Reduce ws[2][NBLK][Hc] -> dgamma[Hc], dbeta[Hc].
// Grid: 16 column-groups x 32 row-chunks = 512 blocks; each thread sums 64
// partials for one output element, then one atomicAdd (32 adds/address).
constexpr int K2_THREADS = 256;
constexpr int K2_RCHUNK  = 64;
constexpr int K2_CG      = (2 * Hc) / K2_THREADS;   // 16
constexpr int K2_RC      = NBLK / K2_RCHUNK;        // 32

__global__ __launch_bounds__(K2_THREADS) void ln_bwd_param_reduce(
    const float* __restrict__ ws, float* __restrict__ out)
{
    const int cg = blockIdx.x % K2_CG;
    const int rc = blockIdx.x / K2_CG;
    const int o  = cg * K2_THREADS + threadIdx.x;   // [0, 4096): dgamma ++ dbeta
    const int which = o >> 11;                       // 0 = dgamma, 1 = dbeta
    const int col   = o & (Hc - 1);

    const float* p = ws + (size_t)which * NBLK * Hc
                        + (size_t)rc * K2_RCHUNK * Hc + col;
    float s = 0.f;
    #pragma unroll 8
    for (int r = 0; r < K2_RCHUNK; ++r) s += p[(size_t)r * Hc];

    atomicAdd(out + (size_t)ROWS * Hc + o, s);
}

extern "C" void kernel_launch(void* const* d_in, const int* in_sizes, int n_in,
                              void* d_out, int out_size, void* d_ws, size_t ws_size,
                              hipStream_t stream) {
    const float* dy    = (const float*)d_in[0];
    const float* x1    = (const float*)d_in[1];
    const float* x2    = (const float*)d_in[2];
    const float* rstd  = (const float*)d_in[3];
    const float* mean  = (const float*)d_in[4];
    const float* gamma = (const float*)d_in[5];
    const float* dsum  = (const float*)d_in[6];
    float* out = (float*)d_out;
    float* ws  = (float*)d_ws;   // needs 2*NBLK*Hc*4B = 33.5 MB

    // Zero dgamma/dbeta region (d_out is poisoned 0xAA before every launch;
    // reduce kernel accumulates with atomics).
    hipMemsetAsync(out + (size_t)ROWS * Hc, 0, 2 * Hc * sizeof(float), stream);

    ln_bwd_main<<<NBLK, THREADS, 0, stream>>>(dy, x1, x2, rstd, mean, gamma, dsum, out, ws);
    ln_bwd_param_reduce<<<K2_CG * K2_RC, K2_THREADS, 0, stream>>>(ws, out);
}